// Round 3
// baseline (62.299 us; speedup 1.0000x reference)
//
#include <hip/hip_runtime.h>
#include <hip/hip_bf16.h>

typedef __bf16 bf16x8 __attribute__((ext_vector_type(8)));
typedef float  f32x4  __attribute__((ext_vector_type(4)));

namespace {
constexpr int kB = 16;
constexpr int kT = 2048;
constexpr int kD = 128;
constexpr int RB = 64;    // rows per block (4 waves x 16 rows)
constexpr int CT = 64;    // columns per LDS tile
constexpr int NT = kT / CT;  // 32 tiles
constexpr float TH_SIM  = 0.9f;
constexpr float TH_DIFF = 0.1f;
constexpr float BIGF    = 1e9f;
}

template <int N>
static __device__ __forceinline__ void wait_vmcnt() {
    asm volatile("s_waitcnt vmcnt(%0)" :: "n"(N) : "memory");
}

// ---- async global->LDS, 16B per lane (dest = wave-uniform base + lane*16)
static __device__ __forceinline__ void gload_lds16(const short* g, short* l) {
    __builtin_amdgcn_global_load_lds(
        (const __attribute__((address_space(1))) void*)g,
        (__attribute__((address_space(3))) void*)l, 16, 0, 0);
}

// ---------------------------------------------------------------- label scan
// One block, 16 waves; wave w = batch w. Zero barriers: per-lane serial
// prefix over 32 labels + 6-step shfl_up wave scan.
__global__ __launch_bounds__(1024) void scan_kernel(const int* __restrict__ label,
                                                    int* __restrict__ perm,
                                                    int* __restrict__ cFarr) {
    const int b    = threadIdx.x >> 6;
    const int lane = threadIdx.x & 63;
    const int* lb  = label + b * kT;
    const int base = lane * 32;
    int loc[32], cnt = 0;
    #pragma unroll
    for (int j = 0; j < 32; ++j) { loc[j] = (lb[base + j] == 0); cnt += loc[j]; }
    int inc = cnt;
    #pragma unroll
    for (int m = 1; m < 64; m <<= 1) {
        const int v = __shfl_up(inc, m);
        if (lane >= m) inc += v;
    }
    const int total = __shfl(inc, 63);
    if (lane == 0) cFarr[b] = total;
    int run = inc - cnt;                      // exclusive prefix of fakes
    #pragma unroll
    for (int j = 0; j < 32; ++j) {
        const int i = base + j;
        perm[b * kT + i] = loc[j] ? run : (total + i - run);
        run += loc[j];
    }
}

// ---------------------------------------------------------------- normalize + scatter
__global__ __launch_bounds__(256) void nrm_kernel(const float* __restrict__ emb,
                                                  const int* __restrict__ perm,
                                                  __hip_bfloat16* __restrict__ out) {
    const int wave = threadIdx.x >> 6;
    const int lane = threadIdx.x & 63;
    const int row  = blockIdx.x * 4 + wave;
    const float2 v = *reinterpret_cast<const float2*>(emb + (size_t)row * kD + lane * 2);
    float ss = v.x * v.x + v.y * v.y;
    #pragma unroll
    for (int m = 1; m < 64; m <<= 1) ss += __shfl_xor(ss, m);
    const float inv = ss > 0.f ? rsqrtf(ss) : 0.f;
    const int b   = row >> 11;
    const int dst = perm[row];
    __hip_bfloat162 o;
    o.x = __float2bfloat16(v.x * inv);
    o.y = __float2bfloat16(v.y * inv);
    *reinterpret_cast<__hip_bfloat162*>(out + ((size_t)(b * kT + dst)) * kD + lane * 2) = o;
}

// ---------------------------------------------------------------- main
// A-frags carry the row sign (real rows negated), so per-value stats cost
// exactly one v_min (MODE1's negate is a free input modifier).
// MODE 0: all cols fake; 1: all cols real; 2: mixed (boundary tile).
template <int MODE>
__device__ __forceinline__ void compute_tile(const short* __restrict__ buf,
                                             const bf16x8 (&afrag)[4],
                                             float (&u1)[4], float (&u2)[4],
                                             int lo, int hi, int colBase, int cf) {
    #pragma unroll
    for (int g = 0; g < 4; ++g) {
        const int col = g * 16 + lo;
        bf16x8 bfrag[4];
        #pragma unroll
        for (int kk = 0; kk < 4; ++kk) {
            const int sh = (kk * 32 + hi * 8) ^ ((col & 7) << 3);
            bfrag[kk] = *reinterpret_cast<const bf16x8*>(&buf[col * kD + sh]);
        }
        f32x4 acc = {0.f, 0.f, 0.f, 0.f};
        __builtin_amdgcn_s_setprio(1);
        #pragma unroll
        for (int kk = 0; kk < 4; ++kk)
            acc = __builtin_amdgcn_mfma_f32_16x16x32_bf16(afrag[kk], bfrag[kk], acc, 0, 0, 0);
        __builtin_amdgcn_s_setprio(0);
        if (MODE == 0) {
            #pragma unroll
            for (int r = 0; r < 4; ++r) u1[r] = fminf(u1[r], acc[r]);
        } else if (MODE == 1) {
            #pragma unroll
            for (int r = 0; r < 4; ++r) u2[r] = fminf(u2[r], -acc[r]);
        } else {
            const bool cfake = (colBase + col) < cf;
            #pragma unroll
            for (int r = 0; r < 4; ++r) {
                u1[r] = fminf(u1[r], cfake ? acc[r] : BIGF);
                u2[r] = fminf(u2[r], cfake ? BIGF : -acc[r]);
            }
        }
    }
}

__global__ __launch_bounds__(256, 3) void crloss_main(const __hip_bfloat16* __restrict__ nrm,
                                                      const int* __restrict__ cFarr,
                                                      float* __restrict__ partials) {
    __shared__ __align__(16) short lds[3][CT * kD];   // 3 x 16 KiB ring
    const int bid  = blockIdx.x;
    const int b    = bid >> 5;
    const int rb   = bid & 31;
    const int tid  = threadIdx.x;
    const int wave = tid >> 6;
    const int lane = tid & 63;
    const int lo   = lane & 15;
    const int hi   = lane >> 4;

    const short* nb = reinterpret_cast<const short*>(nrm) + (size_t)b * kT * kD;
    const int cf = cFarr[b];
    const int wave_row0 = rb * RB + wave * 16;

    // A fragments: lane holds row (lane&15), k = (lane>>4)*8 + e within 32-k block
    bf16x8 afrag[4];
    #pragma unroll
    for (int kk = 0; kk < 4; ++kk)
        afrag[kk] = *reinterpret_cast<const bf16x8*>(
            nb + (size_t)(wave_row0 + lo) * kD + kk * 32 + hi * 8);

    // fold row sign into A: negate real rows (bf16 sign-bit XOR)
    if (wave_row0 + lo >= cf) {
        #pragma unroll
        for (int kk = 0; kk < 4; ++kk) {
            unsigned* u = reinterpret_cast<unsigned*>(&afrag[kk]);
            #pragma unroll
            for (int q = 0; q < 4; ++q) u[q] ^= 0x80008000u;
        }
    }

    float u1[4], u2[4];
    #pragma unroll
    for (int r = 0; r < 4; ++r) { u1[r] = BIGF; u2[r] = BIGF; }

    // staging: 1024 x 16B chunks; pre-swizzled global source, linear LDS dest
    auto stage = [&](int ct, int bufIdx) {
        #pragma unroll
        for (int p = 0; p < 4; ++p) {
            const int unit = p * 4 + wave;
            const int c    = unit * 64 + lane;
            const int col  = c >> 4;
            const int sh   = ((c & 15) * 8) ^ ((col & 7) << 3);
            gload_lds16(nb + (size_t)(ct * CT + col) * kD + sh,
                        &lds[bufIdx][unit * 512]);
        }
    };

    const int  ctF    = cf >> 6;
    const bool hasMix = (cf & 63) != 0;

    stage(0, 0); stage(1, 1); stage(2, 2);     // 12 loads in flight / wave
    for (int ct = 0; ct < NT; ++ct) {
        if (ct < NT - 2)       wait_vmcnt<8>();   // tile ct arrived; 2 tiles stay in flight
        else if (ct == NT - 2) wait_vmcnt<4>();
        else                   wait_vmcnt<0>();
        __builtin_amdgcn_s_barrier();
        __builtin_amdgcn_sched_barrier(0);
        const short* buf = lds[ct % 3];
        if (ct < ctF)
            compute_tile<0>(buf, afrag, u1, u2, lo, hi, ct * CT, cf);
        else if (ct == ctF && hasMix)
            compute_tile<2>(buf, afrag, u1, u2, lo, hi, ct * CT, cf);
        else
            compute_tile<1>(buf, afrag, u1, u2, lo, hi, ct * CT, cf);
        __builtin_amdgcn_s_barrier();            // all waves done reading buf
        if (ct + 3 < NT) stage(ct + 3, ct % 3);  // refill just-freed buffer
    }

    // merge the 16 col-lanes (same hi => same rows)
    #pragma unroll
    for (int m = 1; m <= 8; m <<= 1) {
        #pragma unroll
        for (int r = 0; r < 4; ++r) {
            u1[r] = fminf(u1[r], __shfl_xor(u1[r], m));
            u2[r] = fminf(u2[r], __shfl_xor(u2[r], m));
        }
    }

    // per-row losses; fake rows: minS=u1, maxO=-u2; real rows: minS=u2, maxO=-u1
    float sF = 0.f, sR = 0.f;
    if (lo == 0) {
        #pragma unroll
        for (int r = 0; r < 4; ++r) {
            const int  row = wave_row0 + hi * 4 + r;
            const bool f   = row < cf;
            const float mn = f ? u1[r] : u2[r];
            const float mx = f ? -u2[r] : -u1[r];
            const float l  = fmaxf(TH_SIM - mn, 0.f) + fmaxf(mx - TH_DIFF, 0.f);
            if (f) sF += l; else sR += l;
        }
    }
    #pragma unroll
    for (int m = 1; m < 64; m <<= 1) {
        sF += __shfl_xor(sF, m);
        sR += __shfl_xor(sR, m);
    }

    __shared__ float wsum[4][2];
    if (lane == 0) { wsum[wave][0] = sF; wsum[wave][1] = sR; }
    __syncthreads();
    if (tid == 0) {
        float a = 0.f, c = 0.f;
        for (int w = 0; w < 4; ++w) { a += wsum[w][0]; c += wsum[w][1]; }
        partials[bid * 2]     = a;
        partials[bid * 2 + 1] = c;
    }
}

// ---------------------------------------------------------------- finalize
__global__ __launch_bounds__(512) void crloss_final(const float* __restrict__ partials,
                                                    const int* __restrict__ cFarr,
                                                    float* __restrict__ out) {
    const int t = threadIdx.x;
    float pf = partials[t * 2];
    float pr = partials[t * 2 + 1];
    #pragma unroll
    for (int m = 1; m <= 16; m <<= 1) {   // reduce 32 consecutive entries (one batch)
        pf += __shfl_xor(pf, m);
        pr += __shfl_xor(pr, m);
    }
    __shared__ float sF[16], sR[16];
    if ((t & 31) == 0) { sF[t >> 5] = pf; sR[t >> 5] = pr; }
    __syncthreads();
    if (t == 0) {
        float tot = 0.f;
        for (int b = 0; b < kB; ++b) {
            const int cf = cFarr[b], cr = kT - cf;
            if (cf > 0 && cr > 0)
                tot += sF[b] / (float)cf + sR[b] / (float)cr;
        }
        out[0] = tot / (float)kB;
    }
}

// ---------------------------------------------------------------- launch
extern "C" void kernel_launch(void* const* d_in, const int* in_sizes, int n_in,
                              void* d_out, int out_size, void* d_ws, size_t ws_size,
                              hipStream_t stream) {
    const float* emb   = (const float*)d_in[0];
    const int*   label = (const int*)d_in[1];
    float*       out   = (float*)d_out;

    char* ws = (char*)d_ws;
    __hip_bfloat16* nrm = (__hip_bfloat16*)ws;                       // 8 MiB
    int*   perm     = (int*)(ws + (size_t)kB * kT * kD * 2);         // 128 KiB
    int*   cFarr    = (int*)(ws + (size_t)kB * kT * kD * 2 + kB * kT * 4);
    float* partials = (float*)(ws + (size_t)kB * kT * kD * 2 + kB * kT * 4 + 64);

    scan_kernel<<<1, 1024, 0, stream>>>(label, perm, cFarr);
    nrm_kernel<<<kB * kT / 4, 256, 0, stream>>>(emb, perm, nrm);
    crloss_main<<<kB * (kT / RB), 256, 0, stream>>>(nrm, cFarr, partials);
    crloss_final<<<1, 512, 0, stream>>>(partials, cFarr, out);
}

// Round 4
// 56.548 us; speedup vs baseline: 1.1017x; 1.1017x over previous
//
#include <hip/hip_runtime.h>
#include <hip/hip_bf16.h>

typedef __bf16 bf16x8 __attribute__((ext_vector_type(8)));
typedef float  f32x4  __attribute__((ext_vector_type(4)));

namespace {
constexpr int kB = 16;
constexpr int kT = 2048;
constexpr int kD = 128;
constexpr int RB = 64;       // rows per block; EVERY wave covers all 64 rows
constexpr int CT = 64;       // columns per LDS tile; each wave owns a 16-col slice
constexpr int NT = kT / CT;  // 32 tiles
constexpr float TH_SIM  = 0.9f;
constexpr float TH_DIFF = 0.1f;
constexpr float BIGF    = 1e9f;
}

// ---- async global->LDS, 16B per lane (dest = wave-uniform base + lane*16)
static __device__ __forceinline__ void gload_lds16(const short* g, short* l) {
    __builtin_amdgcn_global_load_lds(
        (const __attribute__((address_space(1))) void*)g,
        (__attribute__((address_space(3))) void*)l, 16, 0, 0);
}

// ---------------------------------------------------------------- label scan
// One block per batch: stable-partition positions (fakes first) + fake count.
__global__ __launch_bounds__(256) void scan_kernel(const int* __restrict__ label,
                                                   int* __restrict__ perm,
                                                   int* __restrict__ cFarr) {
    const int b = blockIdx.x, tid = threadIdx.x;
    const int* lb = label + b * kT;
    int loc[8], cnt = 0;
    #pragma unroll
    for (int j = 0; j < 8; ++j) { loc[j] = (lb[tid * 8 + j] == 0); cnt += loc[j]; }
    __shared__ int s[256];
    s[tid] = cnt;
    __syncthreads();
    for (int off = 1; off < 256; off <<= 1) {
        const int v = (tid >= off) ? s[tid - off] : 0;
        __syncthreads();
        s[tid] += v;
        __syncthreads();
    }
    const int total = s[255];
    if (tid == 0) cFarr[b] = total;
    int run = s[tid] - cnt;
    #pragma unroll
    for (int j = 0; j < 8; ++j) {
        const int i = tid * 8 + j;
        perm[b * kT + i] = loc[j] ? run : (total + i - run);
        run += loc[j];
    }
}

// ---------------------------------------------------------------- normalize + scatter
__global__ __launch_bounds__(256) void nrm_kernel(const float* __restrict__ emb,
                                                  const int* __restrict__ perm,
                                                  __hip_bfloat16* __restrict__ out) {
    const int wave = threadIdx.x >> 6;
    const int lane = threadIdx.x & 63;
    const int row  = blockIdx.x * 4 + wave;
    const float2 v = *reinterpret_cast<const float2*>(emb + (size_t)row * kD + lane * 2);
    float ss = v.x * v.x + v.y * v.y;
    #pragma unroll
    for (int m = 1; m < 64; m <<= 1) ss += __shfl_xor(ss, m);
    const float inv = ss > 0.f ? rsqrtf(ss) : 0.f;
    const int b   = row >> 11;
    const int dst = perm[row];
    __hip_bfloat162 o;
    o.x = __float2bfloat16(v.x * inv);
    o.y = __float2bfloat16(v.y * inv);
    *reinterpret_cast<__hip_bfloat162*>(out + ((size_t)(b * kT + dst)) * kD + lane * 2) = o;
}

// ---------------------------------------------------------------- main
// A-frags carry the row sign (real rows negated): per-value stats = one v_min.
// MODE 0: all cols fake; 1: all cols real; 2: mixed (boundary tile).
template <int MODE>
__device__ __forceinline__ void compute_tile(const short* __restrict__ buf,
                                             const bf16x8 (&afrag)[4][4],
                                             float (&u1)[4][4], float (&u2)[4][4],
                                             int col, int hi, int cGlob, int cf) {
    bf16x8 bfrag[4];
    #pragma unroll
    for (int kk = 0; kk < 4; ++kk) {
        const int sh = (kk * 32 + hi * 8) ^ ((col & 7) << 3);
        bfrag[kk] = *reinterpret_cast<const bf16x8*>(&buf[col * kD + sh]);
    }
    const bool cfake = (MODE == 2) && (cGlob < cf);
    #pragma unroll
    for (int rg = 0; rg < 4; ++rg) {
        f32x4 acc = {0.f, 0.f, 0.f, 0.f};
        #pragma unroll
        for (int kk = 0; kk < 4; ++kk)
            acc = __builtin_amdgcn_mfma_f32_16x16x32_bf16(afrag[rg][kk], bfrag[kk], acc, 0, 0, 0);
        if (MODE == 0) {
            #pragma unroll
            for (int r = 0; r < 4; ++r) u1[rg][r] = fminf(u1[rg][r], acc[r]);
        } else if (MODE == 1) {
            #pragma unroll
            for (int r = 0; r < 4; ++r) u2[rg][r] = fminf(u2[rg][r], -acc[r]);
        } else {
            #pragma unroll
            for (int r = 0; r < 4; ++r) {
                u1[rg][r] = fminf(u1[rg][r], cfake ? acc[r] : BIGF);
                u2[rg][r] = fminf(u2[rg][r], cfake ? BIGF : -acc[r]);
            }
        }
    }
}

__global__ __launch_bounds__(256, 2) void crloss_main(const __hip_bfloat16* __restrict__ nrm,
                                                      const int* __restrict__ cFarr,
                                                      float* __restrict__ partials) {
    __shared__ __align__(16) short lds[2][CT * kD];   // 2 x 16 KiB double buffer
    __shared__ float mrg[2][4][RB];                   // cross-wave stat merge (2 KiB)
    const int bid  = blockIdx.x;
    const int b    = bid >> 5;
    const int rb   = bid & 31;
    const int tid  = threadIdx.x;
    const int wave = tid >> 6;     // = which 16-col slice of each tile
    const int lane = tid & 63;
    const int lo   = lane & 15;
    const int hi   = lane >> 4;

    const short* nb = reinterpret_cast<const short*>(nrm) + (size_t)b * kT * kD;
    const int cf   = cFarr[b];
    const int row0 = rb * RB;
    const int col  = wave * 16 + lo;   // column within tile owned by this lane

    // A fragments for ALL 64 rows: [row-group][k-block]; lane holds row rg*16+lo
    bf16x8 afrag[4][4];
    #pragma unroll
    for (int rg = 0; rg < 4; ++rg) {
        #pragma unroll
        for (int kk = 0; kk < 4; ++kk)
            afrag[rg][kk] = *reinterpret_cast<const bf16x8*>(
                nb + (size_t)(row0 + rg * 16 + lo) * kD + kk * 32 + hi * 8);
        if (row0 + rg * 16 + lo >= cf) {   // fold row sign: negate real rows
            unsigned* u = reinterpret_cast<unsigned*>(&afrag[rg][0]);
            #pragma unroll
            for (int q = 0; q < 16; ++q) u[q] ^= 0x80008000u;
        }
    }

    float u1[4][4], u2[4][4];
    #pragma unroll
    for (int rg = 0; rg < 4; ++rg)
        #pragma unroll
        for (int r = 0; r < 4; ++r) { u1[rg][r] = BIGF; u2[rg][r] = BIGF; }

    // staging: 1024 x 16B chunks; pre-swizzled global source, linear LDS dest
    auto stage = [&](int ct, int bufIdx) {
        #pragma unroll
        for (int p = 0; p < 4; ++p) {
            const int unit = p * 4 + wave;
            const int c    = unit * 64 + lane;
            const int scol = c >> 4;
            const int sh   = ((c & 15) * 8) ^ ((scol & 7) << 3);
            gload_lds16(nb + (size_t)(ct * CT + scol) * kD + sh,
                        &lds[bufIdx][unit * 512]);
        }
    };

    const int  ctF    = cf >> 6;
    const bool hasMix = (cf & 63) != 0;

    stage(0, 0);
    __syncthreads();
    int cur = 0;
    for (int ct = 0; ct < NT; ++ct) {
        if (ct + 1 < NT) stage(ct + 1, cur ^ 1);   // prefetch overlaps compute
        if (ct < ctF)
            compute_tile<0>(lds[cur], afrag, u1, u2, col, hi, ct * CT + col, cf);
        else if (ct == ctF && hasMix)
            compute_tile<2>(lds[cur], afrag, u1, u2, col, hi, ct * CT + col, cf);
        else
            compute_tile<1>(lds[cur], afrag, u1, u2, col, hi, ct * CT + col, cf);
        __syncthreads();   // drains prefetch + guards buffer reuse
        cur ^= 1;
    }

    // merge the 16 col-lanes (same hi => same rows)
    #pragma unroll
    for (int m = 1; m <= 8; m <<= 1) {
        #pragma unroll
        for (int rg = 0; rg < 4; ++rg)
            #pragma unroll
            for (int r = 0; r < 4; ++r) {
                u1[rg][r] = fminf(u1[rg][r], __shfl_xor(u1[rg][r], m));
                u2[rg][r] = fminf(u2[rg][r], __shfl_xor(u2[rg][r], m));
            }
    }

    // cross-wave merge via LDS: each wave covered the same 64 rows, diff cols
    if (lo == 0) {
        #pragma unroll
        for (int rg = 0; rg < 4; ++rg)
            #pragma unroll
            for (int r = 0; r < 4; ++r) {
                mrg[0][wave][rg * 16 + hi * 4 + r] = u1[rg][r];
                mrg[1][wave][rg * 16 + hi * 4 + r] = u2[rg][r];
            }
    }
    __syncthreads();
    if (tid < RB) {
        const int row = tid;
        float a1 = BIGF, a2 = BIGF;
        #pragma unroll
        for (int w = 0; w < 4; ++w) {
            a1 = fminf(a1, mrg[0][w][row]);
            a2 = fminf(a2, mrg[1][w][row]);
        }
        const bool f   = (row0 + row) < cf;
        const float mn = f ? a1 : a2;
        const float mx = f ? -a2 : -a1;
        const float l  = fmaxf(TH_SIM - mn, 0.f) + fmaxf(mx - TH_DIFF, 0.f);
        float sF = f ? l : 0.f;
        float sR = f ? 0.f : l;
        #pragma unroll
        for (int m = 1; m < 64; m <<= 1) {
            sF += __shfl_xor(sF, m);
            sR += __shfl_xor(sR, m);
        }
        if (tid == 0) {
            partials[bid * 2]     = sF;
            partials[bid * 2 + 1] = sR;
        }
    }
}

// ---------------------------------------------------------------- finalize
__global__ __launch_bounds__(512) void crloss_final(const float* __restrict__ partials,
                                                    const int* __restrict__ cFarr,
                                                    float* __restrict__ out) {
    const int t = threadIdx.x;
    float pf = partials[t * 2];
    float pr = partials[t * 2 + 1];
    #pragma unroll
    for (int m = 1; m <= 16; m <<= 1) {   // reduce 32 consecutive entries (one batch)
        pf += __shfl_xor(pf, m);
        pr += __shfl_xor(pr, m);
    }
    __shared__ float sF[16], sR[16];
    if ((t & 31) == 0) { sF[t >> 5] = pf; sR[t >> 5] = pr; }
    __syncthreads();
    if (t == 0) {
        float tot = 0.f;
        for (int b = 0; b < kB; ++b) {
            const int cf = cFarr[b], cr = kT - cf;
            if (cf > 0 && cr > 0)
                tot += sF[b] / (float)cf + sR[b] / (float)cr;
        }
        out[0] = tot / (float)kB;
    }
}

// ---------------------------------------------------------------- launch
extern "C" void kernel_launch(void* const* d_in, const int* in_sizes, int n_in,
                              void* d_out, int out_size, void* d_ws, size_t ws_size,
                              hipStream_t stream) {
    const float* emb   = (const float*)d_in[0];
    const int*   label = (const int*)d_in[1];
    float*       out   = (float*)d_out;

    char* ws = (char*)d_ws;
    __hip_bfloat16* nrm = (__hip_bfloat16*)ws;                       // 8 MiB
    int*   perm     = (int*)(ws + (size_t)kB * kT * kD * 2);         // 128 KiB
    int*   cFarr    = (int*)(ws + (size_t)kB * kT * kD * 2 + kB * kT * 4);
    float* partials = (float*)(ws + (size_t)kB * kT * kD * 2 + kB * kT * 4 + 64);

    scan_kernel<<<kB, 256, 0, stream>>>(label, perm, cFarr);
    nrm_kernel<<<kB * kT / 4, 256, 0, stream>>>(emb, perm, nrm);
    crloss_main<<<kB * (kT / RB), 256, 0, stream>>>(nrm, cFarr, partials);
    crloss_final<<<1, 512, 0, stream>>>(partials, cFarr, out);
}